// Round 7
// baseline (247.662 us; speedup 1.0000x reference)
//
#include <hip/hip_runtime.h>

#define NUM_CLASS 20
#define IGNORE_V 255
#define WW 32
#define HH 256
#define DDEPTH 256
#define NVOX (DDEPTH * HH * WW)   // 2,097,152 voxels
#define CHUNK 1024                // voxels per block (256 per wave)
#define NBLK (NVOX / CHUNK)       // 2048 blocks

// Fine-grained waits, AITER-style: never drain to 0 until the tail.
#define WAITVM(N)  asm volatile("s_waitcnt vmcnt(" #N ")" ::: "memory")
#define WAITLGKM0  asm volatile("s_waitcnt lgkmcnt(0)" ::: "memory")

// sum_c |onehot_c(a) - onehot_c(b)|  (IGNORE -> all-zero onehot)
__device__ __forceinline__ float fpair(int a, int b) {
    return (a == b) ? 0.0f : ((a == IGNORE_V || b == IGNORE_V) ? 1.0f : 2.0f);
}

// Async DMA: 64 lanes x 16B -> 1KB global->LDS, zero result VGPRs.
// gsrc per-lane; ldst wave-uniform base (HW adds lane*16).
__device__ __forceinline__ void stage16(const float* gsrc, float* ldst) {
    __builtin_amdgcn_global_load_lds(
        (const __attribute__((address_space(1))) void*)gsrc,
        (__attribute__((address_space(3))) void*)ldst,
        16, 0, 0);
}

// Wave-private software pipeline: each wave stages and consumes its own
// 256-voxel strip; NO __syncthreads in the class loop. Ping-pong 5-class
// buffers; always >=5 DMAs in flight except at the tail.
__global__ __launch_bounds__(256) void pal_main(
    const float* __restrict__ pred,
    const int*   __restrict__ tgt,
    const float* __restrict__ cw,
    float2*      __restrict__ partial)
{
    __shared__ __align__(16) float lbuf[4][2][5][256];   // 40 KB
    __shared__ float lcw[NUM_CLASS];
    if (threadIdx.x < NUM_CLASS) lcw[threadIdx.x] = cw[threadIdx.x];
    __syncthreads();   // once, at top; K-loop below is barrier-free

    const int tid  = threadIdx.x;
    const int lane = tid & 63;
    const int wid  = tid >> 6;
    const int base = blockIdx.x * CHUNK;
    const int v0   = base + tid * 4;          // this thread's 4-voxel run
    const int w0   = v0 & (WW - 1);
    const int h    = (v0 >> 5) & (HH - 1);
    const int d    = v0 >> 13;

    // ---- issue target + neighbor loads FIRST (oldest in vmcnt queue) ----
    const int4 t4  = *reinterpret_cast<const int4*>(tgt + v0);
    const int tm1  = tgt[v0 - ((w0 != 0) ? 1 : 0)];
    const int tp4  = tgt[v0 + 3 + ((w0 != WW - 4) ? 1 : 0)];
    const int4 tu4 = *reinterpret_cast<const int4*>(tgt + v0 - ((h != 0)          ? WW      : 0));
    const int4 td4 = *reinterpret_cast<const int4*>(tgt + v0 + ((h != HH - 1)     ? WW      : 0));
    const int4 tb4 = *reinterpret_cast<const int4*>(tgt + v0 - ((d != 0)          ? WW * HH : 0));
    const int4 tf4 = *reinterpret_cast<const int4*>(tgt + v0 + ((d != DDEPTH - 1) ? WW * HH : 0));

    const int t[4] = {t4.x, t4.y, t4.z, t4.w};
    const float* gw = pred + base + wid * 256 + lane * 4;   // per-lane src

    float s[4]  = {0.f, 0.f, 0.f, 0.f};
    float pt[4] = {0.f, 0.f, 0.f, 0.f};

    auto consume = [&](int b, int c0) {
        #pragma unroll
        for (int k = 0; k < 5; k++) {
            const float4 x = *reinterpret_cast<const float4*>(&lbuf[wid][b][k][lane * 4]);
            const int c = c0 + k;
            const float xx[4] = {x.x, x.y, x.z, x.w};
            #pragma unroll
            for (int j = 0; j < 4; j++) {
                s[j] += __expf(xx[j]);
                if (t[j] == c) pt[j] = xx[j];
            }
        }
        WAITLGKM0;   // ds_reads retired before this buffer is re-filled
    };

    #pragma unroll
    for (int k = 0; k < 5; k++) stage16(gw + (size_t)k        * NVOX, &lbuf[wid][0][k][0]);
    #pragma unroll
    for (int k = 0; k < 5; k++) stage16(gw + (size_t)(5 + k)  * NVOX, &lbuf[wid][1][k][0]);
    WAITVM(5);  consume(0, 0);      // targets + buf0 done; buf1 in flight
    #pragma unroll
    for (int k = 0; k < 5; k++) stage16(gw + (size_t)(10 + k) * NVOX, &lbuf[wid][0][k][0]);
    WAITVM(5);  consume(1, 5);
    #pragma unroll
    for (int k = 0; k < 5; k++) stage16(gw + (size_t)(15 + k) * NVOX, &lbuf[wid][1][k][0]);
    WAITVM(5);  consume(0, 10);
    WAITVM(0);  consume(1, 15);

    // ---- LGA + loss ----
    const int tu[4] = {tu4.x, tu4.y, tu4.z, tu4.w};
    const int td[4] = {td4.x, td4.y, td4.z, td4.w};
    const int tb[4] = {tb4.x, tb4.y, tb4.z, tb4.w};
    const int tf[4] = {tf4.x, tf4.y, tf4.z, tf4.w};
    const float scH = (h == 0 || h == HH - 1)     ? 1.0f : 0.5f;
    const float scD = (d == 0 || d == DDEPTH - 1) ? 1.0f : 0.5f;

    float num = 0.0f, den = 0.0f;
    #pragma unroll
    for (int j = 0; j < 4; j++) {
        const int tj = t[j];
        if (tj != IGNORE_V) {
            const int wj = w0 + j;
            const int tL = (j > 0) ? t[j-1] : ((w0 == 0)      ? t[0] : tm1);
            const int tR = (j < 3) ? t[j+1] : ((w0 == WW - 4) ? t[3] : tp4);
            const float scW = (wj == 0 || wj == WW - 1) ? 1.0f : 0.5f;
            const float lga = scW * fpair(tL, tR)
                            + scH * fpair(tu[j], td[j])
                            + scD * fpair(tb[j], tf[j]);
            const float wt = lcw[tj];
            num += wt * (__logf(s[j]) - pt[j]) * (1.0f + lga);
            den += wt;
        }
    }

    // ---- wave + block reduction -> one partial per block, no atomics ----
    #pragma unroll
    for (int off = 32; off > 0; off >>= 1) {
        num += __shfl_down(num, off);
        den += __shfl_down(den, off);
    }
    __shared__ float sn[4], sd[4];
    if (lane == 0) { sn[wid] = num; sd[wid] = den; }
    __syncthreads();
    if (tid == 0)
        partial[blockIdx.x] = make_float2((sn[0] + sn[1]) + (sn[2] + sn[3]),
                                          (sd[0] + sd[1]) + (sd[2] + sd[3]));
}

// Single block reduces the 2048 partials (16 KB).
__global__ __launch_bounds__(256) void pal_final(
    const float2* __restrict__ partial, float* __restrict__ out)
{
    const float4* p4 = reinterpret_cast<const float4*>(partial);  // 1024 float4
    float num = 0.f, den = 0.f;
    #pragma unroll
    for (int k = 0; k < 4; k++) {
        const float4 f = p4[threadIdx.x + 256 * k];
        num += f.x + f.z;
        den += f.y + f.w;
    }
    #pragma unroll
    for (int off = 32; off > 0; off >>= 1) {
        num += __shfl_down(num, off);
        den += __shfl_down(den, off);
    }
    __shared__ float sn[4], sd[4];
    const int lane = threadIdx.x & 63;
    const int wid  = threadIdx.x >> 6;
    if (lane == 0) { sn[wid] = num; sd[wid] = den; }
    __syncthreads();
    if (threadIdx.x == 0)
        out[0] = ((sn[0] + sn[1]) + (sn[2] + sn[3])) /
                 ((sd[0] + sd[1]) + (sd[2] + sd[3]));
}

extern "C" void kernel_launch(void* const* d_in, const int* in_sizes, int n_in,
                              void* d_out, int out_size, void* d_ws, size_t ws_size,
                              hipStream_t stream) {
    const float* pred = (const float*)d_in[0];
    const int*   tgt  = (const int*)d_in[1];
    const float* cw   = (const float*)d_in[2];
    float*  out     = (float*)d_out;
    float2* partial = (float2*)d_ws;

    pal_main<<<NBLK, 256, 0, stream>>>(pred, tgt, cw, partial);
    pal_final<<<1, 256, 0, stream>>>(partial, out);
}

// Round 8
// 245.587 us; speedup vs baseline: 1.0084x; 1.0084x over previous
//
#include <hip/hip_runtime.h>

#define NUM_CLASS 20
#define IGNORE_V 255
#define WW 32
#define HH 256
#define DDEPTH 256
#define NVOX (DDEPTH * HH * WW)   // 2,097,152 voxels
#define CHUNK 1024                // voxels per block (256 per wave)
#define NBLK (NVOX / CHUNK)       // 2048 blocks

// sum_c |onehot_c(a) - onehot_c(b)|  (IGNORE -> all-zero onehot)
__device__ __forceinline__ float fpair(int a, int b) {
    return (a == b) ? 0.0f : ((a == IGNORE_V || b == IGNORE_V) ? 1.0f : 2.0f);
}

// Async DMA: 64 lanes x 16B -> 1KB global->LDS, zero result VGPRs.
// gsrc per-lane; ldst wave-uniform base (HW adds lane*16).
__device__ __forceinline__ void stage16(const float* gsrc, float* ldst) {
    __builtin_amdgcn_global_load_lds(
        (const __attribute__((address_space(1))) void*)gsrc,
        (__attribute__((address_space(3))) void*)ldst,
        16, 0, 0);
}

// Hybrid staging: per phase, 5 classes go global->LDS via DMA (LDS-DMA queue)
// and 5 classes go global->VGPR via float4 loads (vector writeback queue).
// The two request paths fill independently -> ~2x outstanding bytes per CU.
__global__ __launch_bounds__(256) void pal_main(
    const float* __restrict__ pred,
    const int*   __restrict__ tgt,
    const float* __restrict__ cw,
    float2*      __restrict__ partial)
{
    __shared__ __align__(16) float lbuf[5][CHUNK];   // 20 KB -> 7+ blocks/CU
    __shared__ float lcw[NUM_CLASS];
    if (threadIdx.x < NUM_CLASS) lcw[threadIdx.x] = cw[threadIdx.x];

    const int tid  = threadIdx.x;
    const int lane = tid & 63;
    const int wid  = tid >> 6;
    const int base = blockIdx.x * CHUNK;
    const int v0   = base + tid * 4;          // this thread's 4-voxel run
    const int w0   = v0 & (WW - 1);
    const int h    = (v0 >> 5) & (HH - 1);
    const int d    = v0 >> 13;

    // ---- targets + neighbors ----
    const int4 t4  = *reinterpret_cast<const int4*>(tgt + v0);
    const int tm1  = tgt[v0 - ((w0 != 0) ? 1 : 0)];
    const int tp4  = tgt[v0 + 3 + ((w0 != WW - 4) ? 1 : 0)];
    const int4 tu4 = *reinterpret_cast<const int4*>(tgt + v0 - ((h != 0)          ? WW      : 0));
    const int4 td4 = *reinterpret_cast<const int4*>(tgt + v0 + ((h != HH - 1)     ? WW      : 0));
    const int4 tb4 = *reinterpret_cast<const int4*>(tgt + v0 - ((d != 0)          ? WW * HH : 0));
    const int4 tf4 = *reinterpret_cast<const int4*>(tgt + v0 + ((d != DDEPTH - 1) ? WW * HH : 0));
    const int t[4] = {t4.x, t4.y, t4.z, t4.w};

    const float* gw = pred + base + wid * 256 + lane * 4;  // per-lane DMA src
    const float* gt = pred + v0;                           // per-thread direct src

    float s[4]  = {0.f, 0.f, 0.f, 0.f};
    float pt[4] = {0.f, 0.f, 0.f, 0.f};

    __syncthreads();   // lcw visible

    #pragma unroll
    for (int ph = 0; ph < 2; ph++) {
        const int cD = ph * 10;        // 5 classes via LDS-DMA
        const int cV = ph * 10 + 5;    // 5 classes via direct VGPR loads

        // issue DMAs first (independent queue) ...
        #pragma unroll
        for (int k = 0; k < 5; k++)
            stage16(gw + (size_t)(cD + k) * NVOX, &lbuf[k][wid * 256]);
        // ... then direct loads (vector writeback queue)
        float4 x[5];
        #pragma unroll
        for (int k = 0; k < 5; k++)
            x[k] = *reinterpret_cast<const float4*>(gt + (size_t)(cV + k) * NVOX);

        // consume direct-load classes while DMAs land
        #pragma unroll
        for (int k = 0; k < 5; k++) {
            const int c = cV + k;
            const float xx[4] = {x[k].x, x[k].y, x[k].z, x[k].w};
            #pragma unroll
            for (int j = 0; j < 4; j++) {
                s[j] += __expf(xx[j]);
                if (t[j] == c) pt[j] = xx[j];
            }
        }

        __syncthreads();   // DMA drain + barrier

        // consume LDS classes
        #pragma unroll
        for (int k = 0; k < 5; k++) {
            const float4 x2 = *reinterpret_cast<const float4*>(&lbuf[k][tid * 4]);
            const int c = cD + k;
            const float xx[4] = {x2.x, x2.y, x2.z, x2.w};
            #pragma unroll
            for (int j = 0; j < 4; j++) {
                s[j] += __expf(xx[j]);
                if (t[j] == c) pt[j] = xx[j];
            }
        }
        __syncthreads();   // reads done before LDS reuse
    }

    // ---- LGA + loss ----
    const int tu[4] = {tu4.x, tu4.y, tu4.z, tu4.w};
    const int td[4] = {td4.x, td4.y, td4.z, td4.w};
    const int tb[4] = {tb4.x, tb4.y, tb4.z, tb4.w};
    const int tf[4] = {tf4.x, tf4.y, tf4.z, tf4.w};
    const float scH = (h == 0 || h == HH - 1)     ? 1.0f : 0.5f;
    const float scD = (d == 0 || d == DDEPTH - 1) ? 1.0f : 0.5f;

    float num = 0.0f, den = 0.0f;
    #pragma unroll
    for (int j = 0; j < 4; j++) {
        const int tj = t[j];
        if (tj != IGNORE_V) {
            const int wj = w0 + j;
            const int tL = (j > 0) ? t[j-1] : ((w0 == 0)      ? t[0] : tm1);
            const int tR = (j < 3) ? t[j+1] : ((w0 == WW - 4) ? t[3] : tp4);
            const float scW = (wj == 0 || wj == WW - 1) ? 1.0f : 0.5f;
            const float lga = scW * fpair(tL, tR)
                            + scH * fpair(tu[j], td[j])
                            + scD * fpair(tb[j], tf[j]);
            const float wt = lcw[tj];
            num += wt * (__logf(s[j]) - pt[j]) * (1.0f + lga);
            den += wt;
        }
    }

    // ---- wave + block reduction -> one partial per block, no atomics ----
    #pragma unroll
    for (int off = 32; off > 0; off >>= 1) {
        num += __shfl_down(num, off);
        den += __shfl_down(den, off);
    }
    __shared__ float sn[4], sd[4];
    if (lane == 0) { sn[wid] = num; sd[wid] = den; }
    __syncthreads();
    if (tid == 0)
        partial[blockIdx.x] = make_float2((sn[0] + sn[1]) + (sn[2] + sn[3]),
                                          (sd[0] + sd[1]) + (sd[2] + sd[3]));
}

// Single block reduces the 2048 partials (16 KB).
__global__ __launch_bounds__(256) void pal_final(
    const float2* __restrict__ partial, float* __restrict__ out)
{
    const float4* p4 = reinterpret_cast<const float4*>(partial);  // 1024 float4
    float num = 0.f, den = 0.f;
    #pragma unroll
    for (int k = 0; k < 4; k++) {
        const float4 f = p4[threadIdx.x + 256 * k];
        num += f.x + f.z;
        den += f.y + f.w;
    }
    #pragma unroll
    for (int off = 32; off > 0; off >>= 1) {
        num += __shfl_down(num, off);
        den += __shfl_down(den, off);
    }
    __shared__ float sn[4], sd[4];
    const int lane = threadIdx.x & 63;
    const int wid  = threadIdx.x >> 6;
    if (lane == 0) { sn[wid] = num; sd[wid] = den; }
    __syncthreads();
    if (threadIdx.x == 0)
        out[0] = ((sn[0] + sn[1]) + (sn[2] + sn[3])) /
                 ((sd[0] + sd[1]) + (sd[2] + sd[3]));
}

extern "C" void kernel_launch(void* const* d_in, const int* in_sizes, int n_in,
                              void* d_out, int out_size, void* d_ws, size_t ws_size,
                              hipStream_t stream) {
    const float* pred = (const float*)d_in[0];
    const int*   tgt  = (const int*)d_in[1];
    const float* cw   = (const float*)d_in[2];
    float*  out     = (float*)d_out;
    float2* partial = (float2*)d_ws;

    pal_main<<<NBLK, 256, 0, stream>>>(pred, tgt, cw, partial);
    pal_final<<<1, 256, 0, stream>>>(partial, out);
}